// Round 3
// baseline (546.613 us; speedup 1.0000x reference)
//
#include <hip/hip_runtime.h>

#define Bn  8
#define Cn  256
#define KCn 32
#define Nn  16384   // 128*128

typedef __attribute__((ext_vector_type(8))) short bf16x8;   // 8 bf16 (4 VGPRs)
typedef __attribute__((ext_vector_type(4))) short short4v;  // 4 bf16 (8 B)
typedef __attribute__((ext_vector_type(4))) float f32x4;    // MFMA acc

__device__ __forceinline__ float elup1(float v) {
    return v > 0.0f ? v + 1.0f : __expf(v);
}
__device__ __forceinline__ short f2bf(float f) {   // fp32 -> bf16 (RNE)
    unsigned u = __float_as_uint(f);
    return (short)((u + 0x7FFFu + ((u >> 16) & 1u)) >> 16);
}

// ---------------------------------------------------------------------------
// Prep: Wk, Wq fp32 -> bf16 (row-major [kf][c]), so the GEMM kernels can load
// A-fragments straight from global (L2-broadcast) with no LDS W tile.
// ---------------------------------------------------------------------------
__global__ void k_prep(const float* __restrict__ Wk, const float* __restrict__ Wq,
                       unsigned short* __restrict__ Wkbf, unsigned short* __restrict__ Wqbf) {
    const int i = blockIdx.x * 512 + threadIdx.x;   // grid 16 * 512 = 8192
    Wkbf[i] = (unsigned short)f2bf(Wk[i]);
    Wqbf[i] = (unsigned short)f2bf(Wq[i]);
}

// ---------------------------------------------------------------------------
// Pass 1 (MFMA): per 128-px chunk (1024 blocks = 4 blocks/CU, 32 waves/CU):
//   GEMM1: D[kf][px] = Wk·X (K=c, 8 chunks of 32, x staged bf16 in LDS,
//          next-iter loads + W frags issued early -> latency hidden)
//   km=elup1(D+bk) -> kml, Z via 16-lane shfl reduce + atomics
//   GEMM2: S[c][kf] += X·KM^T (K=px=128, A re-read from global/L2)
// Frag maps (verified r1): A lane l holds A[l&15][8*(l>>4)+j]; B lane l holds
// B[8*(l>>4)+j][l&15]; C/D col=l&15, row=4*(l>>4)+j.
// ---------------------------------------------------------------------------
__global__ __launch_bounds__(512, 8) void k_km_S(const float* __restrict__ x,
                                                 const unsigned short* __restrict__ Wkbf,
                                                 const float* __restrict__ bk,
                                                 float* __restrict__ S,
                                                 float* __restrict__ Z) {
    __shared__ short xs[128][40];    // x chunk bf16 [px][c32] (10 KB, 2-way max)
    __shared__ short kml[32][136];   // km bf16 [kf][px128] (8.7 KB)
    __shared__ float bkl[KCn];

    const int t = threadIdx.x, b = blockIdx.y, n0 = blockIdx.x * 128;
    const int lane = t & 63, wv = t >> 6;
    const int g = lane >> 4, l15 = lane & 15;
    const int pxw = wv * 16;                 // wave's 16-px tile
    const float* xb = x + (size_t)b * Cn * Nn;
    if (t < KCn) bkl[t] = bk[t];

    const int px = t & 127, ch = t >> 7;     // 4 groups x 8 channels staging
    const float* xpp = xb + n0 + px;
    float ld[8];
#pragma unroll
    for (int i = 0; i < 8; ++i) ld[i] = xpp[(size_t)(ch * 8 + i) * Nn];
    const unsigned short* wk0 = Wkbf + l15 * Cn;
    const unsigned short* wk1 = Wkbf + (16 + l15) * Cn;
    bf16x8 wa0 = *(const bf16x8*)(wk0);
    bf16x8 wa1 = *(const bf16x8*)(wk1);

    // ---- GEMM1: km = Wk · X ----
    f32x4 acc1[2] = {};
    for (int kc = 0; kc < 8; ++kc) {
        __syncthreads();                     // xs free (prev readers done)
        bf16x8 v;
#pragma unroll
        for (int i = 0; i < 8; ++i) v[i] = f2bf(ld[i]);
        *(bf16x8*)&xs[px][ch * 8] = v;
        __syncthreads();                     // xs ready
        bf16x8 wn0 = wa0, wn1 = wa1;
        if (kc < 7) {                        // issue next tile early (T14)
            const float* sp = xpp + (size_t)((kc + 1) * 32 + ch * 8) * Nn;
#pragma unroll
            for (int i = 0; i < 8; ++i) ld[i] = sp[(size_t)i * Nn];
            wn0 = *(const bf16x8*)(wk0 + (kc + 1) * 32);
            wn1 = *(const bf16x8*)(wk1 + (kc + 1) * 32);
        }
        const bf16x8 bf0 = *(const bf16x8*)&xs[pxw + l15][g * 8];
        acc1[0] = __builtin_amdgcn_mfma_f32_16x16x32_bf16(wa0, bf0, acc1[0], 0, 0, 0);
        acc1[1] = __builtin_amdgcn_mfma_f32_16x16x32_bf16(wa1, bf0, acc1[1], 0, 0, 0);
        wa0 = wn0; wa1 = wn1;
    }

    // ---- epilogue: elu+1 -> kml, Z reduce (16-lane groups) ----
#pragma unroll
    for (int mt = 0; mt < 2; ++mt)
#pragma unroll
        for (int j = 0; j < 4; ++j) {
            const int kf = mt * 16 + g * 4 + j;
            const float vv = elup1(acc1[mt][j] + bkl[kf]);
            kml[kf][pxw + l15] = f2bf(vv);
            float s = vv;
            s += __shfl_xor(s, 1); s += __shfl_xor(s, 2);
            s += __shfl_xor(s, 4); s += __shfl_xor(s, 8);
            if (l15 == 0) atomicAdd(&Z[b * KCn + kf], s);
        }
    __syncthreads();   // kml visible to all waves

    // ---- GEMM2: S[c][kf] += X · KM^T (wave owns 32 c rows) ----
    f32x4 acc2[2][2] = {};
    const int crow = wv * 32;
#pragma unroll
    for (int ks = 0; ks < 4; ++ks) {
        bf16x8 a2[2];
#pragma unroll
        for (int mt = 0; mt < 2; ++mt) {
            const float* ap = xb + (size_t)(crow + mt * 16 + l15) * Nn + n0 + ks * 32 + g * 8;
            const float4 f0 = *(const float4*)ap;
            const float4 f1 = *(const float4*)(ap + 4);
            bf16x8 v;
            v[0] = f2bf(f0.x); v[1] = f2bf(f0.y); v[2] = f2bf(f0.z); v[3] = f2bf(f0.w);
            v[4] = f2bf(f1.x); v[5] = f2bf(f1.y); v[6] = f2bf(f1.z); v[7] = f2bf(f1.w);
            a2[mt] = v;
        }
        const bf16x8 b20 = *(const bf16x8*)&kml[l15][ks * 32 + g * 8];
        const bf16x8 b21 = *(const bf16x8*)&kml[16 + l15][ks * 32 + g * 8];
        acc2[0][0] = __builtin_amdgcn_mfma_f32_16x16x32_bf16(a2[0], b20, acc2[0][0], 0, 0, 0);
        acc2[0][1] = __builtin_amdgcn_mfma_f32_16x16x32_bf16(a2[0], b21, acc2[0][1], 0, 0, 0);
        acc2[1][0] = __builtin_amdgcn_mfma_f32_16x16x32_bf16(a2[1], b20, acc2[1][0], 0, 0, 0);
        acc2[1][1] = __builtin_amdgcn_mfma_f32_16x16x32_bf16(a2[1], b21, acc2[1][1], 0, 0, 0);
    }
    float* Sb = S + (size_t)b * Cn * KCn;   // S layout [b][c][kf]
#pragma unroll
    for (int mt = 0; mt < 2; ++mt)
#pragma unroll
        for (int nt = 0; nt < 2; ++nt)
#pragma unroll
            for (int j = 0; j < 4; ++j)
                atomicAdd(&Sb[(crow + mt * 16 + g * 4 + j) * KCn + nt * 16 + l15],
                          acc2[mt][nt][j]);
}

// ---------------------------------------------------------------------------
// Pass 2 (tiny): KVT[b][vc][kf] = bv[vc]*Z[kf] + sum_c Wv[vc][c]*S[b][c][kf]
// ---------------------------------------------------------------------------
__global__ __launch_bounds__(256) void k_kv(const float* __restrict__ Wv,
                                            const float* __restrict__ bv,
                                            const float* __restrict__ S,
                                            const float* __restrict__ Z,
                                            unsigned short* __restrict__ KVT) {
    __shared__ float Sl[Cn][KCn];   // 32 KB
    __shared__ float zl[KCn];
    const int t = threadIdx.x;
    const int b = blockIdx.y;
    const int vc0 = blockIdx.x * 32;
    const float* Sb = S + (size_t)b * Cn * KCn;
#pragma unroll
    for (int i = 0; i < 32; ++i) ((float*)Sl)[i * 256 + t] = Sb[i * 256 + t];
    if (t < KCn) zl[t] = Z[b * KCn + t];
    __syncthreads();
    const int vc = vc0 + (t >> 3);
    const int kq = (t & 7) * 4;
    const float bvv = bv[vc];
    f32x4 acc;
#pragma unroll
    for (int i = 0; i < 4; ++i) acc[i] = bvv * zl[kq + i];
    const float* wv = Wv + (size_t)vc * Cn;
#pragma unroll 4
    for (int c = 0; c < Cn; ++c) {
        const float w = wv[c];
        const f32x4 s4 = *(const f32x4*)&Sl[c][kq];
#pragma unroll
        for (int i = 0; i < 4; ++i) acc[i] += w * s4[i];
    }
    unsigned short* kp = KVT + ((size_t)b * Cn + vc) * KCn + kq;
    ushort4 o;
    o.x = (unsigned short)f2bf(acc[0]); o.y = (unsigned short)f2bf(acc[1]);
    o.z = (unsigned short)f2bf(acc[2]); o.w = (unsigned short)f2bf(acc[3]);
    *(ushort4*)kp = o;
}

// ---------------------------------------------------------------------------
// Pass 3 (MFMA): 128-px chunks, same pipelined GEMM1 (qm = elup1(Wq·X+bq));
// qml overlaid on xs after a barrier (LDS ~31 KB -> 4 blocks/CU);
// GEMM2: U[vc][px] = KVT·QM with Z as augmented row 256 -> qz; fp32 epilogue.
// ---------------------------------------------------------------------------
__global__ __launch_bounds__(512, 8) void k_out(const float* __restrict__ x,
                                                const unsigned short* __restrict__ Wqbf,
                                                const float* __restrict__ bq,
                                                const unsigned short* __restrict__ KVT,
                                                const float* __restrict__ Z,
                                                const float* __restrict__ gamma,
                                                float* __restrict__ out) {
    __shared__ short xsu[128 * 40];  // xs[128][40]; after barrier reused as qml[128][32]
    __shared__ short kvtl[272][40];  // KV^T bf16 [vc][kf]; row 256 = Z; 257..271 = 0
    __shared__ float bql[KCn];

    const int t = threadIdx.x, b = blockIdx.y, n0 = blockIdx.x * 128;
    const int lane = t & 63, wv = t >> 6;
    const int g = lane >> 4, l15 = lane & 15;
    const int pxw = wv * 16;
    const float* xb = x + (size_t)b * Cn * Nn;

    {   // stage KVT (+Z row, zero pad rows), bq  — BOTH 8-elt halves per thread
        const int vc = t >> 1, half = t & 1;
        const bf16x8* src = (const bf16x8*)(KVT + ((size_t)b * Cn + vc) * KCn + half * 16);
        *(bf16x8*)&kvtl[vc][half * 16]     = src[0];
        *(bf16x8*)&kvtl[vc][half * 16 + 8] = src[1];
        if (t < KCn) { bql[t] = bq[t]; kvtl[256][t] = f2bf(Z[b * KCn + t]); }
        for (int i = t; i < 15 * 40; i += 512) kvtl[257 + i / 40][i % 40] = 0;
    }

    const int px = t & 127, ch = t >> 7;
    const float* xpp = xb + n0 + px;
    float ld[8];
#pragma unroll
    for (int i = 0; i < 8; ++i) ld[i] = xpp[(size_t)(ch * 8 + i) * Nn];
    const unsigned short* wq0 = Wqbf + l15 * Cn;
    const unsigned short* wq1 = Wqbf + (16 + l15) * Cn;
    bf16x8 wa0 = *(const bf16x8*)(wq0);
    bf16x8 wa1 = *(const bf16x8*)(wq1);

    // ---- GEMM1: qm = Wq · X (pipelined, identical structure to pass 1) ----
    short (*xs)[40] = (short(*)[40])xsu;
    f32x4 acc1[2] = {};
    for (int kc = 0; kc < 8; ++kc) {
        __syncthreads();
        bf16x8 v;
#pragma unroll
        for (int i = 0; i < 8; ++i) v[i] = f2bf(ld[i]);
        *(bf16x8*)&xs[px][ch * 8] = v;
        __syncthreads();
        bf16x8 wn0 = wa0, wn1 = wa1;
        if (kc < 7) {
            const float* sp = xpp + (size_t)((kc + 1) * 32 + ch * 8) * Nn;
#pragma unroll
            for (int i = 0; i < 8; ++i) ld[i] = sp[(size_t)i * Nn];
            wn0 = *(const bf16x8*)(wq0 + (kc + 1) * 32);
            wn1 = *(const bf16x8*)(wq1 + (kc + 1) * 32);
        }
        const bf16x8 bf0 = *(const bf16x8*)&xs[pxw + l15][g * 8];
        acc1[0] = __builtin_amdgcn_mfma_f32_16x16x32_bf16(wa0, bf0, acc1[0], 0, 0, 0);
        acc1[1] = __builtin_amdgcn_mfma_f32_16x16x32_bf16(wa1, bf0, acc1[1], 0, 0, 0);
        wa0 = wn0; wa1 = wn1;
    }
    __syncthreads();                 // all xs reads done -> safe to overlay qml

    // ---- qm (unscaled) -> qml[px][kf] (wave-local rows, no barrier after) ----
    short* qml = xsu;                // [128][32]
#pragma unroll
    for (int mt = 0; mt < 2; ++mt) {
        short4v q4;
#pragma unroll
        for (int j = 0; j < 4; ++j)
            q4[j] = f2bf(elup1(acc1[mt][j] + bql[mt * 16 + g * 4 + j]));
        *(short4v*)&qml[(pxw + l15) * 32 + mt * 16 + g * 4] = q4;
    }

    // ---- GEMM2 + epilogue ----
    const bf16x8 qb0 = *(const bf16x8*)&qml[(pxw + l15) * 32 + g * 8];
    f32x4 u0 = {};
    {   // qz via augmented Z row (row 256)
        const bf16x8 az = *(const bf16x8*)&kvtl[256 + l15][g * 8];
        u0 = __builtin_amdgcn_mfma_f32_16x16x32_bf16(az, qb0, u0, 0, 0, 0);
    }
    const float qz = __shfl(u0[0], l15);      // row 256 -> lanes 0..15, reg 0
    const float r = gamma[0] / fmaxf(qz, 1e-6f);
    const float* xr = xb + n0 + pxw + l15;
    float* ob = out + (size_t)b * Cn * Nn + n0 + pxw + l15;
#pragma unroll 4
    for (int mt = 0; mt < 16; ++mt) {
        const bf16x8 a = *(const bf16x8*)&kvtl[mt * 16 + l15][g * 8];
        f32x4 c0 = {};
        c0 = __builtin_amdgcn_mfma_f32_16x16x32_bf16(a, qb0, c0, 0, 0, 0);
#pragma unroll
        for (int j = 0; j < 4; ++j) {
            const size_t ro = (size_t)(mt * 16 + g * 4 + j) * Nn;
            ob[ro] = c0[j] * r + xr[ro];
        }
    }
}

// ---------------------------------------------------------------------------
extern "C" void kernel_launch(void* const* d_in, const int* in_sizes, int n_in,
                              void* d_out, int out_size, void* d_ws, size_t ws_size,
                              hipStream_t stream) {
    const float* x     = (const float*)d_in[0];
    const float* Wq    = (const float*)d_in[1];
    const float* bq    = (const float*)d_in[2];
    const float* Wk    = (const float*)d_in[3];
    const float* bk    = (const float*)d_in[4];
    const float* Wv    = (const float*)d_in[5];
    const float* bv    = (const float*)d_in[6];
    const float* gamma = (const float*)d_in[7];
    float* out = (float*)d_out;

    // ws: S f32 [B][C][KC] | Z f32 [B][KC] | KVT bf16 [B][C][KC] | Wkbf | Wqbf
    float* S = (float*)d_ws;
    float* Z = S + (size_t)Bn * Cn * KCn;
    unsigned short* KVT  = (unsigned short*)(Z + (size_t)Bn * KCn);
    unsigned short* Wkbf = KVT + (size_t)Bn * Cn * KCn;
    unsigned short* Wqbf = Wkbf + (size_t)KCn * Cn;

    hipMemsetAsync(d_ws, 0, ((size_t)Bn * Cn * KCn + Bn * KCn) * sizeof(float), stream);
    k_prep<<<dim3(16), 512, 0, stream>>>(Wk, Wq, Wkbf, Wqbf);
    k_km_S<<<dim3(128, Bn), 512, 0, stream>>>(x, Wkbf, bk, S, Z);
    k_kv  <<<dim3(8, Bn), 256, 0, stream>>>(Wv, bv, S, Z, KVT);
    k_out <<<dim3(128, Bn), 512, 0, stream>>>(x, Wqbf, bq, KVT, Z, gamma, out);
}

// Round 4
// 388.093 us; speedup vs baseline: 1.4085x; 1.4085x over previous
//
#include <hip/hip_runtime.h>

#define Bn  8
#define Cn  256
#define KCn 32
#define Nn  16384   // 128*128
#define CW  512     // px chunk width (2-KB DRAM runs per channel per block)
#define NCH (Nn / CW)   // 32 chunks

typedef __attribute__((ext_vector_type(8))) short bf16x8;   // 8 bf16 (4 VGPRs)
typedef __attribute__((ext_vector_type(4))) short short4v;  // 4 bf16 (8 B)
typedef __attribute__((ext_vector_type(4))) float f32x4;    // MFMA acc

__device__ __forceinline__ float elup1(float v) {
    return v > 0.0f ? v + 1.0f : __expf(v);
}
__device__ __forceinline__ short f2bf(float f) {   // fp32 -> bf16 (RNE)
    unsigned u = __float_as_uint(f);
    return (short)((u + 0x7FFFu + ((u >> 16) & 1u)) >> 16);
}

// ---------------------------------------------------------------------------
// Prep: Wk, Wq fp32 -> bf16 [kf][c] for register-direct A-fragments.
// ---------------------------------------------------------------------------
__global__ void k_prep(const float* __restrict__ Wk, const float* __restrict__ Wq,
                       unsigned short* __restrict__ Wkbf, unsigned short* __restrict__ Wqbf) {
    const int i = blockIdx.x * 512 + threadIdx.x;   // 16*512 = 8192
    Wkbf[i] = (unsigned short)f2bf(Wk[i]);
    Wqbf[i] = (unsigned short)f2bf(Wq[i]);
}

// ---------------------------------------------------------------------------
// Pass 1: per 512-px chunk, barrier-free GEMM1 (B-frags register-direct from
// global), then GEMM2 into S. Z via per-block partials (NO atomics).
// Frag maps (r1-verified): A lane l: A[l&15][8g+j]; B lane l: B[8g+j][l&15];
// C/D: col=l&15, row=4g+j.
// grid (32, B), 512 thr (8 waves, 64 px each for GEMM1, 32 c each for GEMM2).
// ---------------------------------------------------------------------------
__global__ __launch_bounds__(512, 4) void k_km_S(const float* __restrict__ x,
                                                 const unsigned short* __restrict__ Wkbf,
                                                 const float* __restrict__ bk,
                                                 float* __restrict__ S,
                                                 float* __restrict__ Zpart) {
    __shared__ short kml[KCn][520];   // [kf][px] bf16; 1040-B rows (16-al, 2-way banks)
    __shared__ float zred[8][KCn];

    const int t = threadIdx.x, b = blockIdx.y, n0 = blockIdx.x * CW;
    const int lane = t & 63, wv = t >> 6;
    const int g = lane >> 4, l15 = lane & 15;
    const int pxw = wv * 64;           // wave's 64-px slice (4 nt tiles)
    const float* xb = x + (size_t)b * Cn * Nn;

    // ---- GEMM1: km = Wk · X  (no LDS, no barriers) ----
    f32x4 acc1[2][4] = {};             // [mt(kf-tile)][nt(px-tile)]
    for (int kc = 0; kc < 8; ++kc) {
        // batch all loads of this k-step first (32-deep MLP per wave)
        float xf[4][8];
#pragma unroll
        for (int nt = 0; nt < 4; ++nt) {
            const float* bp = xb + (size_t)(kc * 32 + g * 8) * Nn + n0 + pxw + nt * 16 + l15;
#pragma unroll
            for (int j = 0; j < 8; ++j) xf[nt][j] = bp[(size_t)j * Nn];
        }
        const bf16x8 wa0 = *(const bf16x8*)(Wkbf + l15 * Cn + kc * 32 + g * 8);
        const bf16x8 wa1 = *(const bf16x8*)(Wkbf + (16 + l15) * Cn + kc * 32 + g * 8);
#pragma unroll
        for (int nt = 0; nt < 4; ++nt) {
            bf16x8 bf;
#pragma unroll
            for (int j = 0; j < 8; ++j) bf[j] = f2bf(xf[nt][j]);
            acc1[0][nt] = __builtin_amdgcn_mfma_f32_16x16x32_bf16(wa0, bf, acc1[0][nt], 0, 0, 0);
            acc1[1][nt] = __builtin_amdgcn_mfma_f32_16x16x32_bf16(wa1, bf, acc1[1][nt], 0, 0, 0);
        }
    }

    // ---- epilogue: elu+1 -> kml, Z partial per wave (no atomics) ----
#pragma unroll
    for (int mt = 0; mt < 2; ++mt)
#pragma unroll
        for (int j = 0; j < 4; ++j) {
            const int kf = mt * 16 + g * 4 + j;
            const float bkv = bk[kf];
            float s = 0.f;
#pragma unroll
            for (int nt = 0; nt < 4; ++nt) {
                const float v = elup1(acc1[mt][nt][j] + bkv);
                kml[kf][pxw + nt * 16 + l15] = f2bf(v);
                s += v;
            }
            s += __shfl_xor(s, 1); s += __shfl_xor(s, 2);
            s += __shfl_xor(s, 4); s += __shfl_xor(s, 8);
            if (l15 == 0) zred[wv][kf] = s;
        }
    __syncthreads();   // kml + zred visible (only barrier in the kernel)
    if (t < KCn) {
        float s = 0.f;
#pragma unroll
        for (int w = 0; w < 8; ++w) s += zred[w][t];
        Zpart[((size_t)b * NCH + blockIdx.x) * KCn + t] = s;
    }

    // ---- GEMM2: S[c][kf] += X · KM^T  (K=512 px; A from global/L3) ----
    f32x4 acc2[2][2] = {};
    const int crow = wv * 32;
#pragma unroll 2
    for (int ks = 0; ks < 16; ++ks) {
        bf16x8 a2[2];
#pragma unroll
        for (int mt = 0; mt < 2; ++mt) {
            const float* ap = xb + (size_t)(crow + mt * 16 + l15) * Nn + n0 + ks * 32 + g * 8;
            const float4 f0 = *(const float4*)ap;
            const float4 f1 = *(const float4*)(ap + 4);
            bf16x8 v;
            v[0] = f2bf(f0.x); v[1] = f2bf(f0.y); v[2] = f2bf(f0.z); v[3] = f2bf(f0.w);
            v[4] = f2bf(f1.x); v[5] = f2bf(f1.y); v[6] = f2bf(f1.z); v[7] = f2bf(f1.w);
            a2[mt] = v;
        }
        const bf16x8 b20 = *(const bf16x8*)&kml[l15][ks * 32 + g * 8];
        const bf16x8 b21 = *(const bf16x8*)&kml[16 + l15][ks * 32 + g * 8];
        acc2[0][0] = __builtin_amdgcn_mfma_f32_16x16x32_bf16(a2[0], b20, acc2[0][0], 0, 0, 0);
        acc2[0][1] = __builtin_amdgcn_mfma_f32_16x16x32_bf16(a2[0], b21, acc2[0][1], 0, 0, 0);
        acc2[1][0] = __builtin_amdgcn_mfma_f32_16x16x32_bf16(a2[1], b20, acc2[1][0], 0, 0, 0);
        acc2[1][1] = __builtin_amdgcn_mfma_f32_16x16x32_bf16(a2[1], b21, acc2[1][1], 0, 0, 0);
    }
    float* Sb = S + (size_t)b * Cn * KCn;   // S layout [b][c][kf]
#pragma unroll
    for (int mt = 0; mt < 2; ++mt)
#pragma unroll
        for (int nt = 0; nt < 2; ++nt)
#pragma unroll
            for (int j = 0; j < 4; ++j)
                atomicAdd(&Sb[(crow + mt * 16 + g * 4 + j) * KCn + nt * 16 + l15],
                          acc2[mt][nt][j]);
}

// ---------------------------------------------------------------------------
// Pass 2 (tiny): reduce Zpart -> zl (+write Zf once), then
// KVT[b][vc][kf] = bv[vc]*zl[kf] + sum_c Wv[vc][c]*S[b][c][kf]   (bf16 out)
// ---------------------------------------------------------------------------
__global__ __launch_bounds__(256) void k_kv(const float* __restrict__ Wv,
                                            const float* __restrict__ bv,
                                            const float* __restrict__ S,
                                            const float* __restrict__ Zpart,
                                            float* __restrict__ Zf,
                                            unsigned short* __restrict__ KVT) {
    __shared__ float Sl[Cn][KCn];   // 32 KB
    __shared__ float zl[KCn];
    const int t = threadIdx.x;
    const int b = blockIdx.y;
    const int vc0 = blockIdx.x * 32;
    const float* Sb = S + (size_t)b * Cn * KCn;
#pragma unroll
    for (int i = 0; i < 32; ++i) ((float*)Sl)[i * 256 + t] = Sb[i * 256 + t];
    if (t < KCn) {
        float s = 0.f;
#pragma unroll 8
        for (int ch = 0; ch < NCH; ++ch) s += Zpart[((size_t)b * NCH + ch) * KCn + t];
        zl[t] = s;
        if (blockIdx.x == 0) Zf[b * KCn + t] = s;
    }
    __syncthreads();
    const int vc = vc0 + (t >> 3);
    const int kq = (t & 7) * 4;
    const float bvv = bv[vc];
    f32x4 acc;
#pragma unroll
    for (int i = 0; i < 4; ++i) acc[i] = bvv * zl[kq + i];
    const float* wv = Wv + (size_t)vc * Cn;
#pragma unroll 4
    for (int c = 0; c < Cn; ++c) {
        const float w = wv[c];
        const f32x4 s4 = *(const f32x4*)&Sl[c][kq];
#pragma unroll
        for (int i = 0; i < 4; ++i) acc[i] += w * s4[i];
    }
    unsigned short* kp = KVT + ((size_t)b * Cn + vc) * KCn + kq;
    ushort4 o;
    o.x = (unsigned short)f2bf(acc[0]); o.y = (unsigned short)f2bf(acc[1]);
    o.z = (unsigned short)f2bf(acc[2]); o.w = (unsigned short)f2bf(acc[3]);
    *(ushort4*)kp = o;
}

// ---------------------------------------------------------------------------
// Pass 3: per 512-px chunk. GEMM1 qm = elup1(Wq·X+bq) register-direct ->
// qml (LDS, wave-local rows). GEMM2 mt-outer: U[vc][px] = KVT·QM; qz from a
// Z-augmented 1-row A (register, lanes l15>0 zero). fp32 epilogue + residual.
// One barrier total (kvtl staging).
// ---------------------------------------------------------------------------
__global__ __launch_bounds__(512, 4) void k_out(const float* __restrict__ x,
                                                const unsigned short* __restrict__ Wqbf,
                                                const float* __restrict__ bq,
                                                const unsigned short* __restrict__ KVT,
                                                const float* __restrict__ Zf,
                                                const float* __restrict__ gamma,
                                                float* __restrict__ out) {
    __shared__ short qml[CW][40];     // [px][kf] bf16, 80-B rows (16-al, 2-way)
    __shared__ short kvtl[Cn][40];    // [vc][kf] bf16

    const int t = threadIdx.x, b = blockIdx.y, n0 = blockIdx.x * CW;
    const int lane = t & 63, wv = t >> 6;
    const int g = lane >> 4, l15 = lane & 15;
    const int pxw = wv * 64;
    const float* xb = x + (size_t)b * Cn * Nn;

    {   // stage KVT (both 16-B halves per thread!)
        const int vc = t >> 1, half = t & 1;
        const bf16x8* src = (const bf16x8*)(KVT + ((size_t)b * Cn + vc) * KCn + half * 16);
        *(bf16x8*)&kvtl[vc][half * 16]     = src[0];
        *(bf16x8*)&kvtl[vc][half * 16 + 8] = src[1];
    }
    __syncthreads();                  // only barrier

    // ---- GEMM1: qm = Wq · X (register-direct B-frags) ----
    f32x4 acc1[2][4] = {};
    for (int kc = 0; kc < 8; ++kc) {
        float xf[4][8];
#pragma unroll
        for (int nt = 0; nt < 4; ++nt) {
            const float* bp = xb + (size_t)(kc * 32 + g * 8) * Nn + n0 + pxw + nt * 16 + l15;
#pragma unroll
            for (int j = 0; j < 8; ++j) xf[nt][j] = bp[(size_t)j * Nn];
        }
        const bf16x8 wa0 = *(const bf16x8*)(Wqbf + l15 * Cn + kc * 32 + g * 8);
        const bf16x8 wa1 = *(const bf16x8*)(Wqbf + (16 + l15) * Cn + kc * 32 + g * 8);
#pragma unroll
        for (int nt = 0; nt < 4; ++nt) {
            bf16x8 bf;
#pragma unroll
            for (int j = 0; j < 8; ++j) bf[j] = f2bf(xf[nt][j]);
            acc1[0][nt] = __builtin_amdgcn_mfma_f32_16x16x32_bf16(wa0, bf, acc1[0][nt], 0, 0, 0);
            acc1[1][nt] = __builtin_amdgcn_mfma_f32_16x16x32_bf16(wa1, bf, acc1[1][nt], 0, 0, 0);
        }
    }

    // ---- qm -> qml (wave-local rows; same-wave RAW, no barrier needed) ----
#pragma unroll
    for (int mt = 0; mt < 2; ++mt)
#pragma unroll
        for (int nt = 0; nt < 4; ++nt) {
            short4v q4;
#pragma unroll
            for (int j = 0; j < 4; ++j)
                q4[j] = f2bf(elup1(acc1[mt][nt][j] + bq[mt * 16 + g * 4 + j]));
            *(short4v*)&qml[pxw + nt * 16 + l15][mt * 16 + g * 4] = q4;
        }

    // ---- GEMM2: mt-outer for sequential output runs ----
    bf16x8 qb[4];
#pragma unroll
    for (int nt = 0; nt < 4; ++nt)
        qb[nt] = *(const bf16x8*)&qml[pxw + nt * 16 + l15][g * 8];

    bf16x8 az = {};                   // 1-row A: row0 = Zf (lanes l15>0 zero)
    if (l15 == 0) {
#pragma unroll
        for (int j = 0; j < 8; ++j) az[j] = f2bf(Zf[b * KCn + g * 8 + j]);
    }
    const float gm = gamma[0];
    float r[4];
#pragma unroll
    for (int nt = 0; nt < 4; ++nt) {
        f32x4 u = {};
        u = __builtin_amdgcn_mfma_f32_16x16x32_bf16(az, qb[nt], u, 0, 0, 0);
        const float qz = __shfl(u[0], l15);   // row 0 lives in lanes 0..15, reg 0
        r[nt] = gm / fmaxf(qz, 1e-6f);
    }

    const float* xr = xb + n0 + pxw;
    float* ob = out + (size_t)b * Cn * Nn + n0 + pxw;
#pragma unroll 2
    for (int mt = 0; mt < 16; ++mt) {
        const bf16x8 a = *(const bf16x8*)&kvtl[mt * 16 + l15][g * 8];
#pragma unroll
        for (int nt = 0; nt < 4; ++nt) {
            f32x4 c0 = {};
            c0 = __builtin_amdgcn_mfma_f32_16x16x32_bf16(a, qb[nt], c0, 0, 0, 0);
#pragma unroll
            for (int j = 0; j < 4; ++j) {
                const size_t ro = (size_t)(mt * 16 + g * 4 + j) * Nn + nt * 16 + l15;
                ob[ro] = c0[j] * r[nt] + xr[ro];
            }
        }
    }
}

// ---------------------------------------------------------------------------
extern "C" void kernel_launch(void* const* d_in, const int* in_sizes, int n_in,
                              void* d_out, int out_size, void* d_ws, size_t ws_size,
                              hipStream_t stream) {
    const float* x     = (const float*)d_in[0];
    const float* Wq    = (const float*)d_in[1];
    const float* bq    = (const float*)d_in[2];
    const float* Wk    = (const float*)d_in[3];
    const float* bk    = (const float*)d_in[4];
    const float* Wv    = (const float*)d_in[5];
    const float* bv    = (const float*)d_in[6];
    const float* gamma = (const float*)d_in[7];
    float* out = (float*)d_out;

    // ws: S f32 [B][C][KC] | Zpart f32 [B][NCH][KC] | Zf f32 [B][KC]
    //   | KVT bf16 [B][C][KC] | Wkbf | Wqbf
    float* S     = (float*)d_ws;
    float* Zpart = S + (size_t)Bn * Cn * KCn;
    float* Zf    = Zpart + (size_t)Bn * NCH * KCn;
    unsigned short* KVT  = (unsigned short*)(Zf + (size_t)Bn * KCn);
    unsigned short* Wkbf = KVT + (size_t)Bn * Cn * KCn;
    unsigned short* Wqbf = Wkbf + (size_t)KCn * Cn;

    hipMemsetAsync(d_ws, 0,
                   ((size_t)Bn * Cn * KCn + (size_t)Bn * NCH * KCn) * sizeof(float),
                   stream);
    k_prep<<<dim3(16), 512, 0, stream>>>(Wk, Wq, Wkbf, Wqbf);
    k_km_S<<<dim3(NCH, Bn), 512, 0, stream>>>(x, Wkbf, bk, S, Zpart);
    k_kv  <<<dim3(8, Bn), 256, 0, stream>>>(Wv, bv, S, Zpart, Zf, KVT);
    k_out <<<dim3(NCH, Bn), 512, 0, stream>>>(x, Wqbf, bq, KVT, Zf, gamma, out);
}

// Round 5
// 322.816 us; speedup vs baseline: 1.6933x; 1.2022x over previous
//
#include <hip/hip_runtime.h>

#define Bn  8
#define Cn  256
#define KCn 32
#define Nn  16384   // 128*128
#define CW  256     // px chunk width (1-KB DRAM runs, 512 blocks = 2/CU)
#define NCH (Nn / CW)   // 64 chunks

typedef __attribute__((ext_vector_type(8))) short bf16x8;   // 8 bf16 (4 VGPRs)
typedef __attribute__((ext_vector_type(4))) float f32x4;    // MFMA acc

__device__ __forceinline__ float elup1(float v) {
    return v > 0.0f ? v + 1.0f : __expf(v);
}
__device__ __forceinline__ short f2bf(float f) {   // fp32 -> bf16 (RNE)
    unsigned u = __float_as_uint(f);
    return (short)((u + 0x7FFFu + ((u >> 16) & 1u)) >> 16);
}
__device__ __forceinline__ bf16x8 cvt8(const float* __restrict__ p) {
    const float4 f0 = *(const float4*)p;
    const float4 f1 = *(const float4*)(p + 4);
    bf16x8 v;
    v[0] = f2bf(f0.x); v[1] = f2bf(f0.y); v[2] = f2bf(f0.z); v[3] = f2bf(f0.w);
    v[4] = f2bf(f1.x); v[5] = f2bf(f1.y); v[6] = f2bf(f1.z); v[7] = f2bf(f1.w);
    return v;
}

// ---------------------------------------------------------------------------
// Pass 1: per 256-px chunk, GEMM1 computes BOTH km = elup1(Wk·X+bk) and
// qm = elup1(Wq·X+bq) from the SAME x fragments (x read once).
//   km -> kml (LDS) -> GEMM2: S[c][kf] += X·KM^T (atomics)
//   qm -> qml global bf16 [b][kf][n]  (pass 3 reads fragments directly)
//   Z per-block partials (no atomics).
// Frag maps (r1-verified): A lane l: A[l&15][8g+j]; B lane l: B[8g+j][l&15];
// C/D: col=l&15, row=4g+j.  grid (64, B), 512 thr.
// ---------------------------------------------------------------------------
__global__ __launch_bounds__(512, 4) void k_km_S(const float* __restrict__ x,
                                                 const float* __restrict__ Wk,
                                                 const float* __restrict__ Wq,
                                                 const float* __restrict__ bk,
                                                 const float* __restrict__ bq,
                                                 float* __restrict__ S,
                                                 float* __restrict__ Zpart,
                                                 unsigned short* __restrict__ qml) {
    __shared__ short kml[KCn][264];   // [kf][px] bf16, 528-B rows
    __shared__ float zred[8][KCn];

    const int t = threadIdx.x, b = blockIdx.y, n0 = blockIdx.x * CW;
    const int lane = t & 63, wv = t >> 6;
    const int g = lane >> 4, l15 = lane & 15;
    const int pxw = wv * 32;           // wave's 32-px slice (2 nt tiles)
    const float* xb = x + (size_t)b * Cn * Nn;

    // ---- GEMM1: km and qm from shared x fragments (no barriers) ----
    f32x4 akm[2][2] = {}, aqm[2][2] = {};
    for (int kc = 0; kc < 8; ++kc) {
        const int c0 = kc * 32 + g * 8;
        const bf16x8 wk0 = cvt8(Wk + l15 * Cn + c0);
        const bf16x8 wk1 = cvt8(Wk + (16 + l15) * Cn + c0);
        const bf16x8 wq0 = cvt8(Wq + l15 * Cn + c0);
        const bf16x8 wq1 = cvt8(Wq + (16 + l15) * Cn + c0);
        float xf[2][8];
#pragma unroll
        for (int nt = 0; nt < 2; ++nt) {
            const float* bp = xb + (size_t)c0 * Nn + n0 + pxw + nt * 16 + l15;
#pragma unroll
            for (int j = 0; j < 8; ++j) xf[nt][j] = bp[(size_t)j * Nn];
        }
#pragma unroll
        for (int nt = 0; nt < 2; ++nt) {
            bf16x8 bf;
#pragma unroll
            for (int j = 0; j < 8; ++j) bf[j] = f2bf(xf[nt][j]);
            akm[0][nt] = __builtin_amdgcn_mfma_f32_16x16x32_bf16(wk0, bf, akm[0][nt], 0, 0, 0);
            akm[1][nt] = __builtin_amdgcn_mfma_f32_16x16x32_bf16(wk1, bf, akm[1][nt], 0, 0, 0);
            aqm[0][nt] = __builtin_amdgcn_mfma_f32_16x16x32_bf16(wq0, bf, aqm[0][nt], 0, 0, 0);
            aqm[1][nt] = __builtin_amdgcn_mfma_f32_16x16x32_bf16(wq1, bf, aqm[1][nt], 0, 0, 0);
        }
    }

    // ---- epilogue: km -> kml + Z partial; qm -> qml global ----
#pragma unroll
    for (int mt = 0; mt < 2; ++mt)
#pragma unroll
        for (int j = 0; j < 4; ++j) {
            const int kf = mt * 16 + g * 4 + j;
            const float bkv = bk[kf], bqv = bq[kf];
            float s = 0.f;
#pragma unroll
            for (int nt = 0; nt < 2; ++nt) {
                const int px = pxw + nt * 16 + l15;
                const float v = elup1(akm[mt][nt][j] + bkv);
                kml[kf][px] = f2bf(v);
                s += v;
                const float q = elup1(aqm[mt][nt][j] + bqv);
                qml[((size_t)b * KCn + kf) * Nn + n0 + px] = (unsigned short)f2bf(q);
            }
            s += __shfl_xor(s, 1); s += __shfl_xor(s, 2);
            s += __shfl_xor(s, 4); s += __shfl_xor(s, 8);
            if (l15 == 0) zred[wv][kf] = s;
        }
    __syncthreads();   // kml + zred visible
    if (t < KCn) {
        float s = 0.f;
#pragma unroll
        for (int w = 0; w < 8; ++w) s += zred[w][t];
        Zpart[((size_t)b * NCH + blockIdx.x) * KCn + t] = s;
    }

    // ---- GEMM2: S[c][kf] += X · KM^T  (K=256 px; A re-read, L2/L3-hot) ----
    f32x4 acc2[2][2] = {};
    const int crow = wv * 32;
#pragma unroll 2
    for (int ks = 0; ks < 8; ++ks) {
        bf16x8 a2[2];
#pragma unroll
        for (int mt = 0; mt < 2; ++mt)
            a2[mt] = cvt8(xb + (size_t)(crow + mt * 16 + l15) * Nn + n0 + ks * 32 + g * 8);
        const bf16x8 b20 = *(const bf16x8*)&kml[l15][ks * 32 + g * 8];
        const bf16x8 b21 = *(const bf16x8*)&kml[16 + l15][ks * 32 + g * 8];
        acc2[0][0] = __builtin_amdgcn_mfma_f32_16x16x32_bf16(a2[0], b20, acc2[0][0], 0, 0, 0);
        acc2[0][1] = __builtin_amdgcn_mfma_f32_16x16x32_bf16(a2[0], b21, acc2[0][1], 0, 0, 0);
        acc2[1][0] = __builtin_amdgcn_mfma_f32_16x16x32_bf16(a2[1], b20, acc2[1][0], 0, 0, 0);
        acc2[1][1] = __builtin_amdgcn_mfma_f32_16x16x32_bf16(a2[1], b21, acc2[1][1], 0, 0, 0);
    }
    float* Sb = S + (size_t)b * Cn * KCn;   // S layout [b][c][kf]
#pragma unroll
    for (int mt = 0; mt < 2; ++mt)
#pragma unroll
        for (int nt = 0; nt < 2; ++nt)
#pragma unroll
            for (int j = 0; j < 4; ++j)
                atomicAdd(&Sb[(crow + mt * 16 + g * 4 + j) * KCn + nt * 16 + l15],
                          acc2[mt][nt][j]);
}

// ---------------------------------------------------------------------------
// Pass 2 (tiny): reduce Zpart -> zl (+write Zf), then
// KVT[b][vc][kf] = bv[vc]*zl[kf] + sum_c Wv[vc][c]*S[b][c][kf]   (bf16)
// ---------------------------------------------------------------------------
__global__ __launch_bounds__(256) void k_kv(const float* __restrict__ Wv,
                                            const float* __restrict__ bv,
                                            const float* __restrict__ S,
                                            const float* __restrict__ Zpart,
                                            float* __restrict__ Zf,
                                            unsigned short* __restrict__ KVT) {
    __shared__ float Sl[Cn][KCn];   // 32 KB
    __shared__ float zl[KCn];
    const int t = threadIdx.x;
    const int b = blockIdx.y;
    const int vc0 = blockIdx.x * 32;
    const float* Sb = S + (size_t)b * Cn * KCn;
#pragma unroll
    for (int i = 0; i < 32; ++i) ((float*)Sl)[i * 256 + t] = Sb[i * 256 + t];
    if (t < KCn) {
        float s = 0.f;
#pragma unroll 8
        for (int ch = 0; ch < NCH; ++ch) s += Zpart[((size_t)b * NCH + ch) * KCn + t];
        zl[t] = s;
        if (blockIdx.x == 0) Zf[b * KCn + t] = s;
    }
    __syncthreads();
    const int vc = vc0 + (t >> 3);
    const int kq = (t & 7) * 4;
    const float bvv = bv[vc];
    f32x4 acc;
#pragma unroll
    for (int i = 0; i < 4; ++i) acc[i] = bvv * zl[kq + i];
    const float* wv = Wv + (size_t)vc * Cn;
#pragma unroll 4
    for (int c = 0; c < Cn; ++c) {
        const float w = wv[c];
        const f32x4 s4 = *(const f32x4*)&Sl[c][kq];
#pragma unroll
        for (int i = 0; i < 4; ++i) acc[i] += w * s4[i];
    }
    unsigned short* kp = KVT + ((size_t)b * Cn + vc) * KCn + kq;
    ushort4 o;
    o.x = (unsigned short)f2bf(acc[0]); o.y = (unsigned short)f2bf(acc[1]);
    o.z = (unsigned short)f2bf(acc[2]); o.w = (unsigned short)f2bf(acc[3]);
    *(ushort4*)kp = o;
}

// ---------------------------------------------------------------------------
// Pass 3: per 256-px chunk. NO GEMM1 — qm fragments read straight from qml.
// GEMM2: U[vc][px] = KVT·QM; qz via Z-augmented 1-row A. Epilogue staged
// through LDS (double-buffered, 1 barrier/slice) -> 512-B contiguous
// residual reads + out writes. grid (64, B), 512 thr, 2 blocks/CU.
// ---------------------------------------------------------------------------
__global__ __launch_bounds__(512, 4) void k_out(const float* __restrict__ x,
                                                const unsigned short* __restrict__ qml,
                                                const unsigned short* __restrict__ KVT,
                                                const float* __restrict__ Zf,
                                                const float* __restrict__ gamma,
                                                float* __restrict__ out) {
    __shared__ short kvtl[Cn][40];        // [vc][kf] bf16 (20 KB)
    __shared__ float stagef[2][16][260];  // out slice [vc16][px256] (2x16.6 KB)

    const int t = threadIdx.x, b = blockIdx.y, n0 = blockIdx.x * CW;
    const int lane = t & 63, wv = t >> 6;
    const int g = lane >> 4, l15 = lane & 15;
    const int pxw = wv * 32;
    const float* xb = x + (size_t)b * Cn * Nn;

    {   // stage KVT (both 16-B halves per thread)
        const int vc = t >> 1, half = t & 1;
        const bf16x8* src = (const bf16x8*)(KVT + ((size_t)b * Cn + vc) * KCn + half * 16);
        *(bf16x8*)&kvtl[vc][half * 16]     = src[0];
        *(bf16x8*)&kvtl[vc][half * 16 + 8] = src[1];
    }

    // ---- qm B-fragments from global (L2/L3-hot, 8.4 MB buffer) ----
    bf16x8 qb[2];
#pragma unroll
    for (int nt = 0; nt < 2; ++nt) {
        const unsigned short* qp = qml + (size_t)b * KCn * Nn + n0 + pxw + nt * 16 + l15;
#pragma unroll
        for (int j = 0; j < 8; ++j)
            qb[nt][j] = (short)qp[(size_t)(g * 8 + j) * Nn];
    }

    // ---- qz via Z-augmented 1-row A ----
    bf16x8 az = {};
    if (l15 == 0) {
#pragma unroll
        for (int j = 0; j < 8; ++j) az[j] = f2bf(Zf[b * KCn + g * 8 + j]);
    }
    const float gm = gamma[0];
    float r[2];
#pragma unroll
    for (int nt = 0; nt < 2; ++nt) {
        f32x4 u = {};
        u = __builtin_amdgcn_mfma_f32_16x16x32_bf16(az, qb[nt], u, 0, 0, 0);
        const float qz = __shfl(u[0], l15);   // row 0 -> lanes 0..15, reg 0
        r[nt] = gm / fmaxf(qz, 1e-6f);
    }
    __syncthreads();                          // kvtl ready

    // ---- GEMM2 mt-outer + LDS-staged coalesced epilogue ----
    const int srow = t >> 5, scol = (t & 31) * 4;   // writeback mapping
    int buf = 0;
    for (int mt = 0; mt < 16; ++mt) {
#pragma unroll
        for (int nt = 0; nt < 2; ++nt) {
            const bf16x8 a = *(const bf16x8*)&kvtl[mt * 16 + l15][g * 8];
            f32x4 c0 = {};
            c0 = __builtin_amdgcn_mfma_f32_16x16x32_bf16(a, qb[nt], c0, 0, 0, 0);
#pragma unroll
            for (int j = 0; j < 4; ++j)
                stagef[buf][g * 4 + j][pxw + nt * 16 + l15] = c0[j] * r[nt];
        }
        __syncthreads();   // slice staged by all waves
        {
            const int vc = mt * 16 + srow;
            const float* xr = xb + (size_t)vc * Nn + n0;
            float* ob = out + ((size_t)b * Cn + vc) * Nn + n0;
#pragma unroll
            for (int k = 0; k < 2; ++k) {
                const int col = scol + k * 128;
                const float4 sv = *(const float4*)&stagef[buf][srow][col];
                const float4 xv = *(const float4*)(xr + col);
                float4 o;
                o.x = sv.x + xv.x; o.y = sv.y + xv.y;
                o.z = sv.z + xv.z; o.w = sv.w + xv.w;
                *(float4*)(ob + col) = o;
            }
        }
        buf ^= 1;          // next slice stages the other buffer (see r4 notes)
    }
}

// ---------------------------------------------------------------------------
extern "C" void kernel_launch(void* const* d_in, const int* in_sizes, int n_in,
                              void* d_out, int out_size, void* d_ws, size_t ws_size,
                              hipStream_t stream) {
    const float* x     = (const float*)d_in[0];
    const float* Wq    = (const float*)d_in[1];
    const float* bq    = (const float*)d_in[2];
    const float* Wk    = (const float*)d_in[3];
    const float* bk    = (const float*)d_in[4];
    const float* Wv    = (const float*)d_in[5];
    const float* bv    = (const float*)d_in[6];
    const float* gamma = (const float*)d_in[7];
    float* out = (float*)d_out;

    // ws: S f32 [B][C][KC] | Zpart f32 [B][NCH][KC] | Zf f32 [B][KC]
    //   | KVT bf16 [B][C][KC] | qml bf16 [B][KC][N]
    float* S     = (float*)d_ws;
    float* Zpart = S + (size_t)Bn * Cn * KCn;
    float* Zf    = Zpart + (size_t)Bn * NCH * KCn;
    unsigned short* KVT = (unsigned short*)(Zf + (size_t)Bn * KCn);
    unsigned short* qml = KVT + (size_t)Bn * Cn * KCn;

    hipMemsetAsync(d_ws, 0,
                   ((size_t)Bn * Cn * KCn + (size_t)Bn * NCH * KCn) * sizeof(float),
                   stream);
    k_km_S<<<dim3(NCH, Bn), 512, 0, stream>>>(x, Wk, Wq, bk, bq, S, Zpart, qml);
    k_kv  <<<dim3(8, Bn), 256, 0, stream>>>(Wv, bv, S, Zpart, Zf, KVT);
    k_out <<<dim3(NCH, Bn), 512, 0, stream>>>(x, qml, KVT, Zf, gamma, out);
}